// Round 10
// baseline (900.133 us; speedup 1.0000x reference)
//
#include <hip/hip_runtime.h>
#include <cstdint>

typedef _Float16 f16x2 __attribute__((ext_vector_type(2)));

#define L2E 1.44269504f

// sig2(y) = 1/(1+2^-y)  (y pre-scaled by log2e via weights)
__device__ __forceinline__ float sig2(float y) {
  return __builtin_amdgcn_rcpf(1.f + exp2f(-y));
}
// tanh for runtime (unscaled) cell state c
__device__ __forceinline__ float tanhc(float c) {
  return fmaf(2.f, __builtin_amdgcn_rcpf(1.f + exp2f(c * (-2.f * L2E))), -1.f);
}
__device__ __forceinline__ int packf16(float a, float b) {
  f16x2 p; p.x = (_Float16)a; p.y = (_Float16)b;
  return __builtin_bit_cast(int, p);
}
__device__ __forceinline__ float dot2(int w, int h, float acc) {
  return __builtin_amdgcn_fdot2(__builtin_bit_cast(f16x2, w),
                                __builtin_bit_cast(f16x2, h), acc, false);
}
// Quad-lane permute via DPP (~4 cyc VALU).
template <int CTRL>
__device__ __forceinline__ float qp(float v) {
  return __int_as_float(__builtin_amdgcn_update_dpp(
      0, __float_as_int(v), CTRL, 0xF, 0xF, true));
}
#define QP_X1 0xB1  // quad_perm [1,0,3,2]  (lane ^ 1)
#define QP_X2 0x4E  // quad_perm [2,3,0,1]  (lane ^ 2)
// lane ^ 4 via ds_swizzle BitMode: xor=4, and=0x1F -> offset 0x101F
__device__ __forceinline__ float swz4(float v) {
  return __int_as_float(
      __builtin_amdgcn_ds_swizzle(__float_as_int(v), 0x101F));
}

// ---------------------------------------------------------------------------
// R10 = R9 with ONE fix: R9 double-scaled the tanh gate (weights pre-folded
// with 2*L2E AND a runtime S+S doubling -> computed 2*sig(4x)-1). The f32
// convention (R7/R8, verified) is: fold 2*L2E into g-gate weights, then
// sig2(S) directly. absmax 6.5e-2 -> expected ~1.2e-4.
//
// R9 rationale (unchanged): K-EIGHTH / 1024 threads shrinks per-thread regs
// (~105) below the ~124 arch-VGPR cap so the allocator CANNOT park operands
// in AGPRs (R7/R8: parked w[] made full-rate fma effectively ~4-6 cyc,
// VALUBusy 99%). launch_bounds(1024,4) = 4 waves/SIMD. Reduce = verified
// quad transpose-reduce (lambda=e&3) + one ds_swizzle lane^4 hop combining
// half-K quads (same gate map in both quads -> R7 gather reused verbatim).
// hq reads rotated by (j+e)&3 (max 2-way alias, free). Phase 1: 1 chain per
// thread, Whh1 streamed from LDS broadcast (memory clobber per step stops
// LICM hoisting 128 regs of weights).
// ---------------------------------------------------------------------------
__global__ __launch_bounds__(1024, 4) void fused_kernel(
    const float* __restrict__ x, const float* __restrict__ Wih1,
    const float* __restrict__ Whh1, const float* __restrict__ bih1,
    const float* __restrict__ bhh1, const float* __restrict__ Wih2,
    const float* __restrict__ Whh2, const float* __restrict__ bih2,
    const float* __restrict__ bhh2, const float* __restrict__ Wd1,
    const float* __restrict__ bd1, const float* __restrict__ Wd2,
    const float* __restrict__ bd2, float* __restrict__ out) {
  __shared__ __align__(16) float sXf[1026][8];  // h1 sequence, f32 (32.8 KB)
  __shared__ __align__(16) float sHf[2][128];   // double-buffered h, f32
  __shared__ __align__(16) int sWhh1[128];      // lstm1 Whh packed f16x2

  const int b = blockIdx.x;
  const int t = threadIdx.x;

  // ======================== Phase 1: lstm1 (dot2) ========================
  {
    if (t < 128) {  // stage packed, log2e-folded Whh1 (gate g rows x2)
      const int r = t >> 2, j = t & 3;
      const float s = (r >> 3) == 2 ? 2.f * L2E : L2E;
      float2 v = ((const float2*)(Whh1 + r * 8))[j];
      sWhh1[t] = packf16(v.x * s, v.y * s);
    }
    int wxb[32];
#pragma unroll
    for (int r = 0; r < 32; ++r) {
      const float s = (r >> 3) == 2 ? 2.f * L2E : L2E;
      wxb[r] = packf16(Wih1[r] * s, (bih1[r] + bhh1[r]) * s);
    }
    __syncthreads();  // sWhh1 visible

    const float* __restrict__ xp = x + ((size_t)b * 1024 + t) * 16;
    float cc[8];
    int h2[4];
#pragma unroll
    for (int k = 0; k < 8; ++k) cc[k] = 0.f;
#pragma unroll
    for (int j = 0; j < 4; ++j) h2[j] = 0;

    float hn[8];
#pragma unroll 1
    for (int u = 0; u < 16; ++u) {
      asm volatile("" ::: "memory");  // block LICM hoist of sWhh1 reads
      const int xt1 = packf16(xp[u], 1.f);
#pragma unroll
      for (int k = 0; k < 8; ++k) {
        float acc[4];
#pragma unroll
        for (int gi = 0; gi < 4; ++gi) {
          const int r = gi * 8 + k;
          int4 wv = ((const int4*)sWhh1)[r];  // uniform addr -> broadcast
          float a = dot2(wxb[r], xt1, 0.f);
          a = dot2(wv.x, h2[0], a);
          a = dot2(wv.y, h2[1], a);
          a = dot2(wv.z, h2[2], a);
          a = dot2(wv.w, h2[3], a);
          acc[gi] = a;
        }
        float iv = sig2(acc[0]), fv = sig2(acc[1]);
        float gv = fmaf(2.f, sig2(acc[2]), -1.f), ov = sig2(acc[3]);
        cc[k] = fmaf(fv, cc[k], iv * gv);
        hn[k] = ov * tanhc(cc[k]);
      }
#pragma unroll
      for (int j = 0; j < 4; ++j) h2[j] = packf16(hn[2 * j], hn[2 * j + 1]);
    }
    float4* dst = (float4*)sXf[t];
    float4 o0v, o1v;
    o0v.x = hn[0]; o0v.y = hn[1]; o0v.z = hn[2]; o0v.w = hn[3];
    o1v.x = hn[4]; o1v.y = hn[5]; o1v.z = hn[6]; o1v.w = hn[7];
    dst[0] = o0v; dst[1] = o1v;
  }

  // ======================== Phase 2: lstm2 (f32 fma) ========================
  const int m = t >> 3;  // hidden index (0..127)
  const int e = t & 7;   // K-eighth; e&3 = DPP quad lane
  const bool sel0 = (e & 1) != 0;
  const bool sel1 = (e & 2) != 0;
  const bool isg = ((e & 3) == 1);          // lane finalizing the tanh gate
  const int G = ((e & 1) << 1) | ((e >> 1) & 1);  // gate this lane finalizes
  const int xh = (e >> 2);                  // which x-half this lane dots

  // K-eighth e of all 4 gate rows of m, f32, log2e-folded, slot jj rotated
  // by (jj+e)&3 to match the bank-conflict-free hq read pattern.
  float w[64];
#pragma unroll
  for (int g = 0; g < 4; ++g) {
    const float s = (g == 2) ? 2.f * L2E : L2E;
    const float4* p = (const float4*)(Whh2 + (size_t)(g * 128 + m) * 128 + e * 16);
#pragma unroll
    for (int jj = 0; jj < 4; ++jj) {
      float4 v = p[(jj + e) & 3];
      w[g * 16 + 4 * jj + 0] = v.x * s;
      w[g * 16 + 4 * jj + 1] = v.y * s;
      w[g * 16 + 4 * jj + 2] = v.z * s;
      w[g * 16 + 4 * jj + 3] = v.w * s;
    }
  }
#pragma unroll
  for (int i = 0; i < 64; i += 8)
    asm volatile("" : "+v"(w[i]), "+v"(w[i + 1]), "+v"(w[i + 2]),
                      "+v"(w[i + 3]), "+v"(w[i + 4]), "+v"(w[i + 5]),
                      "+v"(w[i + 6]), "+v"(w[i + 7]));

  // Half of gate G's x-row (+ bias once, in the e<4 half).
  float wig[4];
  float bx0;
  {
    const float s = (G == 2) ? 2.f * L2E : L2E;
    const float4 wv = *(const float4*)(Wih2 + (size_t)(G * 128 + m) * 8 + xh * 4);
    wig[0] = wv.x * s; wig[1] = wv.y * s; wig[2] = wv.z * s; wig[3] = wv.w * s;
    bx0 = (e < 4) ? (bih2[G * 128 + m] + bhh2[G * 128 + m]) * s : 0.f;
  }

  // Rotated hq read offsets (float4 units, relative to sHf[BUF] + e*4)
  const int r0 = (0 + e) & 3, r1 = (1 + e) & 3, r2 = (2 + e) & 3, r3 = (3 + e) & 3;

  float hq[16];  // this thread's h-eighth (16 f32), rotated-slot order
#pragma unroll
  for (int i = 0; i < 16; ++i) hq[i] = 0.f;
  float c = 0.f;

  __syncthreads();  // sXf fully written
  float4 xc = ((const float4*)sXf[0])[xh];

#define LSTM2_STEP(BUF, NEXT_IDX)                                          \
  {                                                                        \
    float bx = bx0;                                                        \
    bx = fmaf(wig[0], xc.x, bx);                                           \
    bx = fmaf(wig[1], xc.y, bx);                                           \
    bx = fmaf(wig[2], xc.z, bx);                                           \
    bx = fmaf(wig[3], xc.w, bx);                                           \
    float R0 = 0.f, R1 = 0.f, R2 = 0.f, R3 = 0.f;                          \
    _Pragma("unroll")                                                      \
    for (int j = 0; j < 16; ++j) {                                         \
      R0 = fmaf(w[j], hq[j], R0);                                          \
      R1 = fmaf(w[16 + j], hq[j], R1);                                     \
      R2 = fmaf(w[32 + j], hq[j], R2);                                     \
      R3 = fmaf(w[48 + j], hq[j], R3);                                     \
    }                                                                      \
    float s0 = sel0 ? R0 : R2, s1 = sel0 ? R1 : R3;                        \
    float k0 = sel0 ? R2 : R0, k1 = sel0 ? R3 : R1;                        \
    float S0 = k0 + qp<QP_X1>(s0);                                         \
    float S1 = k1 + qp<QP_X1>(s1);                                         \
    float s2 = sel1 ? S0 : S1;                                             \
    float k2 = sel1 ? S1 : S0;                                             \
    float Sq = k2 + qp<QP_X2>(s2) + bx;                                    \
    float S = Sq + swz4(Sq); /* combine half-K quads (lane^4) */           \
    float sg = sig2(S);      /* g-gate scale is pre-folded in weights */   \
    float act = isg ? fmaf(2.f, sg, -1.f) : sg;                            \
    float v0 = act;                                                        \
    float v1 = qp<QP_X1>(v0);                                              \
    float v2 = qp<QP_X2>(v0);                                              \
    float v3 = qp<QP_X2>(v1);                                              \
    float p01 = sel0 ? v1 : v0, p23 = sel0 ? v3 : v2;                      \
    float q01 = sel0 ? v0 : v1, q23 = sel0 ? v2 : v3;                      \
    float iv = sel1 ? p23 : p01;                                           \
    float fv = sel1 ? p01 : p23;                                           \
    float gv = sel1 ? q23 : q01;                                           \
    float ov = sel1 ? q01 : q23;                                           \
    c = fmaf(fv, c, iv * gv);                                              \
    float hx = ov * tanhc(c);                                              \
    if (e == 0) sHf[BUF][m] = hx;                                          \
    __syncthreads();                                                       \
    {                                                                      \
      const float4* hb = (const float4*)(sHf[BUF]) + e * 4;                \
      float4 A = hb[r0], Bv = hb[r1], C = hb[r2], D = hb[r3];              \
      hq[0] = A.x;   hq[1] = A.y;   hq[2] = A.z;   hq[3] = A.w;            \
      hq[4] = Bv.x;  hq[5] = Bv.y;  hq[6] = Bv.z;  hq[7] = Bv.w;           \
      hq[8] = C.x;   hq[9] = C.y;   hq[10] = C.z;  hq[11] = C.w;           \
      hq[12] = D.x;  hq[13] = D.y;  hq[14] = D.z;  hq[15] = D.w;           \
      xc = ((const float4*)sXf[NEXT_IDX])[xh];                             \
    }                                                                      \
  }

#pragma unroll 1
  for (int ts2 = 0; ts2 < 512; ++ts2) {
    LSTM2_STEP(0, 2 * ts2 + 1)
    LSTM2_STEP(1, 2 * ts2 + 2)
  }
#undef LSTM2_STEP

  // Epilogue: out[b] = (h @ Wd1.T + bd1) @ Wd2.T + bd2; h_T is in sHf[1].
  if (t < 64) {
    float a = bd1[t];
#pragma unroll
    for (int k = 0; k < 128; ++k)
      a = fmaf(Wd1[t * 128 + k], sHf[1][k], a);
    float v = a * Wd2[t];
#pragma unroll
    for (int off = 32; off > 0; off >>= 1) v += __shfl_down(v, off);
    if (t == 0) out[b] = v + bd2[0];
  }
}

extern "C" void kernel_launch(void* const* d_in, const int* in_sizes, int n_in,
                              void* d_out, int out_size, void* d_ws, size_t ws_size,
                              hipStream_t stream) {
  const float* x    = (const float*)d_in[0];
  // d_in[1] is the unused python scalar `data`
  const float* Wih1 = (const float*)d_in[2];
  const float* Whh1 = (const float*)d_in[3];
  const float* bih1 = (const float*)d_in[4];
  const float* bhh1 = (const float*)d_in[5];
  const float* Wih2 = (const float*)d_in[6];
  const float* Whh2 = (const float*)d_in[7];
  const float* bih2 = (const float*)d_in[8];
  const float* bhh2 = (const float*)d_in[9];
  const float* W1   = (const float*)d_in[10];
  const float* b1   = (const float*)d_in[11];
  const float* W2   = (const float*)d_in[12];
  const float* b2   = (const float*)d_in[13];
  float* out = (float*)d_out;

  fused_kernel<<<256, 1024, 0, stream>>>(x, Wih1, Whh1, bih1, bhh1,
                                         Wih2, Whh2, bih2, bhh2,
                                         W1, b1, W2, b2, out);
}

// Round 12
// 888.430 us; speedup vs baseline: 1.0132x; 1.0132x over previous
//
#include <hip/hip_runtime.h>
#include <cstdint>

typedef _Float16 f16x2 __attribute__((ext_vector_type(2)));

#define L2E 1.44269504f

// sig2(y) = 1/(1+2^-y)  (y pre-scaled by log2e via weights)
__device__ __forceinline__ float sig2(float y) {
  return __builtin_amdgcn_rcpf(1.f + exp2f(-y));
}
// tanh for runtime (unscaled) cell state c
__device__ __forceinline__ float tanhc(float c) {
  return fmaf(2.f, __builtin_amdgcn_rcpf(1.f + exp2f(c * (-2.f * L2E))), -1.f);
}
__device__ __forceinline__ int packf16(float a, float b) {
  f16x2 p; p.x = (_Float16)a; p.y = (_Float16)b;
  return __builtin_bit_cast(int, p);
}
__device__ __forceinline__ float dot2(int w, int h, float acc) {
  return __builtin_amdgcn_fdot2(__builtin_bit_cast(f16x2, w),
                                __builtin_bit_cast(f16x2, h), acc, false);
}
// Quad-lane permute via DPP (~4 cyc VALU).
template <int CTRL>
__device__ __forceinline__ float qp(float v) {
  return __int_as_float(__builtin_amdgcn_update_dpp(
      0, __float_as_int(v), CTRL, 0xF, 0xF, true));
}
#define QP_X1 0xB1  // quad_perm [1,0,3,2]  (lane ^ 1)
#define QP_X2 0x4E  // quad_perm [2,3,0,1]  (lane ^ 2)
// lane ^ 4 via ds_swizzle BitMode: xor=4, and=0x1F -> offset 0x101F
__device__ __forceinline__ float swz4(float v) {
  return __int_as_float(
      __builtin_amdgcn_ds_swizzle(__float_as_int(v), 0x101F));
}

// ---------------------------------------------------------------------------
// R12 = R11 resubmitted verbatim (R11 was a container-side infra failure,
// same signature as R3 which ran fine on resubmit as R4). R11 = R10 + two:
//  (1) REGISTER TIER PIN: R10's launch_bounds(1024,4) let the allocator
//      target 8 waves/EU -> 64 VGPRs -> ~105-reg working set SPILLED to
//      scratch (FETCH 9.5->32 MB, WRITE 8KB->13MB, latency on the chain).
//      Now: launch_bounds(1024) + amdgpu_waves_per_eu(4,4) pins exactly
//      4 waves/EU -> 128-reg budget, ~115 live fits, no spill.
//  (2) FULL bank-conflict fix: R10's (jj+e)&3 rotation only de-aliased
//      mod 4; bank-quad = float4-slot mod 8, so e and e+4 still collided
//      2-way (6.7e7 counter). Rotation (jj+(e>>1))&3 makes slot mod 8 =
//      4*(e&1) + (jj+(e>>1))&3 a bijection across the 8 e values ->
//      conflict-free. Same permutation on the w load (dot order-invariant).
// Everything else byte-identical to R10 (passed, absmax 1.2e-4).
// ---------------------------------------------------------------------------
__global__ __launch_bounds__(1024)
__attribute__((amdgpu_waves_per_eu(4, 4))) void fused_kernel(
    const float* __restrict__ x, const float* __restrict__ Wih1,
    const float* __restrict__ Whh1, const float* __restrict__ bih1,
    const float* __restrict__ bhh1, const float* __restrict__ Wih2,
    const float* __restrict__ Whh2, const float* __restrict__ bih2,
    const float* __restrict__ bhh2, const float* __restrict__ Wd1,
    const float* __restrict__ bd1, const float* __restrict__ Wd2,
    const float* __restrict__ bd2, float* __restrict__ out) {
  __shared__ __align__(16) float sXf[1026][8];  // h1 sequence, f32 (32.8 KB)
  __shared__ __align__(16) float sHf[2][128];   // double-buffered h, f32
  __shared__ __align__(16) int sWhh1[128];      // lstm1 Whh packed f16x2

  const int b = blockIdx.x;
  const int t = threadIdx.x;

  // ======================== Phase 1: lstm1 (dot2) ========================
  {
    if (t < 128) {  // stage packed, log2e-folded Whh1 (gate g rows x2)
      const int r = t >> 2, j = t & 3;
      const float s = (r >> 3) == 2 ? 2.f * L2E : L2E;
      float2 v = ((const float2*)(Whh1 + r * 8))[j];
      sWhh1[t] = packf16(v.x * s, v.y * s);
    }
    int wxb[32];
#pragma unroll
    for (int r = 0; r < 32; ++r) {
      const float s = (r >> 3) == 2 ? 2.f * L2E : L2E;
      wxb[r] = packf16(Wih1[r] * s, (bih1[r] + bhh1[r]) * s);
    }
    __syncthreads();  // sWhh1 visible

    const float* __restrict__ xp = x + ((size_t)b * 1024 + t) * 16;
    float cc[8];
    int h2[4];
#pragma unroll
    for (int k = 0; k < 8; ++k) cc[k] = 0.f;
#pragma unroll
    for (int j = 0; j < 4; ++j) h2[j] = 0;

    float hn[8];
#pragma unroll 1
    for (int u = 0; u < 16; ++u) {
      asm volatile("" ::: "memory");  // block LICM hoist of sWhh1 reads
      const int xt1 = packf16(xp[u], 1.f);
#pragma unroll
      for (int k = 0; k < 8; ++k) {
        float acc[4];
#pragma unroll
        for (int gi = 0; gi < 4; ++gi) {
          const int r = gi * 8 + k;
          int4 wv = ((const int4*)sWhh1)[r];  // uniform addr -> broadcast
          float a = dot2(wxb[r], xt1, 0.f);
          a = dot2(wv.x, h2[0], a);
          a = dot2(wv.y, h2[1], a);
          a = dot2(wv.z, h2[2], a);
          a = dot2(wv.w, h2[3], a);
          acc[gi] = a;
        }
        float iv = sig2(acc[0]), fv = sig2(acc[1]);
        float gv = fmaf(2.f, sig2(acc[2]), -1.f), ov = sig2(acc[3]);
        cc[k] = fmaf(fv, cc[k], iv * gv);
        hn[k] = ov * tanhc(cc[k]);
      }
#pragma unroll
      for (int j = 0; j < 4; ++j) h2[j] = packf16(hn[2 * j], hn[2 * j + 1]);
    }
    float4* dst = (float4*)sXf[t];
    float4 o0v, o1v;
    o0v.x = hn[0]; o0v.y = hn[1]; o0v.z = hn[2]; o0v.w = hn[3];
    o1v.x = hn[4]; o1v.y = hn[5]; o1v.z = hn[6]; o1v.w = hn[7];
    dst[0] = o0v; dst[1] = o1v;
  }

  // ======================== Phase 2: lstm2 (f32 fma) ========================
  const int m = t >> 3;  // hidden index (0..127)
  const int e = t & 7;   // K-eighth; e&3 = DPP quad lane
  const bool sel0 = (e & 1) != 0;
  const bool sel1 = (e & 2) != 0;
  const bool isg = ((e & 3) == 1);          // lane finalizing the tanh gate
  const int G = ((e & 1) << 1) | ((e >> 1) & 1);  // gate this lane finalizes
  const int xh = (e >> 2);                  // which x-half this lane dots

  // Conflict-free rotation: slot jj -> (jj + (e>>1)) & 3. float4-slot
  // mod 8 = 4*(e&1) + (jj+(e>>1))&3 is a bijection over e for fixed jj.
  const int rot = (e >> 1) & 3;

  // K-eighth e of all 4 gate rows of m, f32, log2e-folded, slots rotated
  // to match the conflict-free hq read pattern.
  float w[64];
#pragma unroll
  for (int g = 0; g < 4; ++g) {
    const float s = (g == 2) ? 2.f * L2E : L2E;
    const float4* p = (const float4*)(Whh2 + (size_t)(g * 128 + m) * 128 + e * 16);
#pragma unroll
    for (int jj = 0; jj < 4; ++jj) {
      float4 v = p[(jj + rot) & 3];
      w[g * 16 + 4 * jj + 0] = v.x * s;
      w[g * 16 + 4 * jj + 1] = v.y * s;
      w[g * 16 + 4 * jj + 2] = v.z * s;
      w[g * 16 + 4 * jj + 3] = v.w * s;
    }
  }
#pragma unroll
  for (int i = 0; i < 64; i += 8)
    asm volatile("" : "+v"(w[i]), "+v"(w[i + 1]), "+v"(w[i + 2]),
                      "+v"(w[i + 3]), "+v"(w[i + 4]), "+v"(w[i + 5]),
                      "+v"(w[i + 6]), "+v"(w[i + 7]));

  // Half of gate G's x-row (+ bias once, in the e<4 half).
  float wig[4];
  float bx0;
  {
    const float s = (G == 2) ? 2.f * L2E : L2E;
    const float4 wv = *(const float4*)(Wih2 + (size_t)(G * 128 + m) * 8 + xh * 4);
    wig[0] = wv.x * s; wig[1] = wv.y * s; wig[2] = wv.z * s; wig[3] = wv.w * s;
    bx0 = (e < 4) ? (bih2[G * 128 + m] + bhh2[G * 128 + m]) * s : 0.f;
  }

  // Rotated hq read offsets (float4 units, relative to sHf[BUF] + e*4)
  const int r0 = (0 + rot) & 3, r1 = (1 + rot) & 3;
  const int r2 = (2 + rot) & 3, r3 = (3 + rot) & 3;

  float hq[16];  // this thread's h-eighth (16 f32), rotated-slot order
#pragma unroll
  for (int i = 0; i < 16; ++i) hq[i] = 0.f;
  float c = 0.f;

  __syncthreads();  // sXf fully written
  float4 xc = ((const float4*)sXf[0])[xh];

#define LSTM2_STEP(BUF, NEXT_IDX)                                          \
  {                                                                        \
    float bx = bx0;                                                        \
    bx = fmaf(wig[0], xc.x, bx);                                           \
    bx = fmaf(wig[1], xc.y, bx);                                           \
    bx = fmaf(wig[2], xc.z, bx);                                           \
    bx = fmaf(wig[3], xc.w, bx);                                           \
    float R0 = 0.f, R1 = 0.f, R2 = 0.f, R3 = 0.f;                          \
    _Pragma("unroll")                                                      \
    for (int j = 0; j < 16; ++j) {                                         \
      R0 = fmaf(w[j], hq[j], R0);                                          \
      R1 = fmaf(w[16 + j], hq[j], R1);                                     \
      R2 = fmaf(w[32 + j], hq[j], R2);                                     \
      R3 = fmaf(w[48 + j], hq[j], R3);                                     \
    }                                                                      \
    float s0 = sel0 ? R0 : R2, s1 = sel0 ? R1 : R3;                        \
    float k0 = sel0 ? R2 : R0, k1 = sel0 ? R3 : R1;                        \
    float S0 = k0 + qp<QP_X1>(s0);                                         \
    float S1 = k1 + qp<QP_X1>(s1);                                         \
    float s2 = sel1 ? S0 : S1;                                             \
    float k2 = sel1 ? S1 : S0;                                             \
    float Sq = k2 + qp<QP_X2>(s2) + bx;                                    \
    float S = Sq + swz4(Sq); /* combine half-K quads (lane^4) */           \
    float sg = sig2(S);      /* g-gate scale is pre-folded in weights */   \
    float act = isg ? fmaf(2.f, sg, -1.f) : sg;                            \
    float v0 = act;                                                        \
    float v1 = qp<QP_X1>(v0);                                              \
    float v2 = qp<QP_X2>(v0);                                              \
    float v3 = qp<QP_X2>(v1);                                              \
    float p01 = sel0 ? v1 : v0, p23 = sel0 ? v3 : v2;                      \
    float q01 = sel0 ? v0 : v1, q23 = sel0 ? v2 : v3;                      \
    float iv = sel1 ? p23 : p01;                                           \
    float fv = sel1 ? p01 : p23;                                           \
    float gv = sel1 ? q23 : q01;                                           \
    float ov = sel1 ? q01 : q23;                                           \
    c = fmaf(fv, c, iv * gv);                                              \
    float hx = ov * tanhc(c);                                              \
    if (e == 0) sHf[BUF][m] = hx;                                          \
    __syncthreads();                                                       \
    {                                                                      \
      const float4* hb = (const float4*)(sHf[BUF]) + e * 4;                \
      float4 A = hb[r0], Bv = hb[r1], C = hb[r2], D = hb[r3];              \
      hq[0] = A.x;   hq[1] = A.y;   hq[2] = A.z;   hq[3] = A.w;            \
      hq[4] = Bv.x;  hq[5] = Bv.y;  hq[6] = Bv.z;  hq[7] = Bv.w;           \
      hq[8] = C.x;   hq[9] = C.y;   hq[10] = C.z;  hq[11] = C.w;           \
      hq[12] = D.x;  hq[13] = D.y;  hq[14] = D.z;  hq[15] = D.w;           \
      xc = ((const float4*)sXf[NEXT_IDX])[xh];                             \
    }                                                                      \
  }

#pragma unroll 1
  for (int ts2 = 0; ts2 < 512; ++ts2) {
    LSTM2_STEP(0, 2 * ts2 + 1)
    LSTM2_STEP(1, 2 * ts2 + 2)
  }
#undef LSTM2_STEP

  // Epilogue: out[b] = (h @ Wd1.T + bd1) @ Wd2.T + bd2; h_T is in sHf[1].
  if (t < 64) {
    float a = bd1[t];
#pragma unroll
    for (int k = 0; k < 128; ++k)
      a = fmaf(Wd1[t * 128 + k], sHf[1][k], a);
    float v = a * Wd2[t];
#pragma unroll
    for (int off = 32; off > 0; off >>= 1) v += __shfl_down(v, off);
    if (t == 0) out[b] = v + bd2[0];
  }
}

extern "C" void kernel_launch(void* const* d_in, const int* in_sizes, int n_in,
                              void* d_out, int out_size, void* d_ws, size_t ws_size,
                              hipStream_t stream) {
  const float* x    = (const float*)d_in[0];
  // d_in[1] is the unused python scalar `data`
  const float* Wih1 = (const float*)d_in[2];
  const float* Whh1 = (const float*)d_in[3];
  const float* bih1 = (const float*)d_in[4];
  const float* bhh1 = (const float*)d_in[5];
  const float* Wih2 = (const float*)d_in[6];
  const float* Whh2 = (const float*)d_in[7];
  const float* bih2 = (const float*)d_in[8];
  const float* bhh2 = (const float*)d_in[9];
  const float* W1   = (const float*)d_in[10];
  const float* b1   = (const float*)d_in[11];
  const float* W2   = (const float*)d_in[12];
  const float* b2   = (const float*)d_in[13];
  float* out = (float*)d_out;

  fused_kernel<<<256, 1024, 0, stream>>>(x, Wih1, Whh1, bih1, bhh1,
                                         Wih2, Whh2, bih2, bhh2,
                                         W1, b1, W2, b2, out);
}

// Round 13
// 842.271 us; speedup vs baseline: 1.0687x; 1.0548x over previous
//
#include <hip/hip_runtime.h>
#include <cstdint>

typedef _Float16 f16x2 __attribute__((ext_vector_type(2)));
typedef _Float16 f16x8v __attribute__((ext_vector_type(8)));
typedef float f32x4v __attribute__((ext_vector_type(4)));

#define L2E 1.44269504f

// sig2(y) = 1/(1+2^-y)  (y pre-scaled by log2e via weights)
__device__ __forceinline__ float sig2(float y) {
  return __builtin_amdgcn_rcpf(1.f + exp2f(-y));
}
// tanh for runtime (unscaled) cell state c
__device__ __forceinline__ float tanhc(float c) {
  return fmaf(2.f, __builtin_amdgcn_rcpf(1.f + exp2f(c * (-2.f * L2E))), -1.f);
}
__device__ __forceinline__ int packf16(float a, float b) {
  f16x2 p; p.x = (_Float16)a; p.y = (_Float16)b;
  return __builtin_bit_cast(int, p);
}
__device__ __forceinline__ float dot2(int w, int h, float acc) {
  return __builtin_amdgcn_fdot2(__builtin_bit_cast(f16x2, w),
                                __builtin_bit_cast(f16x2, h), acc, false);
}

// ---------------------------------------------------------------------------
// R13: lstm2 matvec via MFMA. The dot2/f32-fma VALU lanes are exhausted:
// dot2 path floor = 136 quarter-rate insts ~= 1150 cyc/step (R4, 659us);
// f32-fma path needs ~200 regs, which the allocator refuses (AGPR-park
// R7/R8, scratch-spill R10/R12). MFMA sidesteps both walls:
//  - 40 x v_mfma_f32_16x16x32_f16 per wave/step (8 N-tiles x [4 H-K-tiles
//    + 1 X-tile]) ~= 194 cyc issue on the MATRIX pipe (vs 1150 VALU).
//  - B-fragments (weights, 160 regs) are read by MFMA natively from AGPRs,
//    so the >124-reg working set parks for FREE (that's what AGPRs are for).
//  - A = h row-vector (M row 0 only; rows 1-15 zero). C/D layout is
//    HW-verified (guide m89): row=(lane>>4)*4+reg, col=lane&15 -> row 0
//    lives in lanes 0-15 reg 0, pointwise = 2 gate-sets/lane there.
//  - A/B per-lane k-maps are identical; any consistent bijective k
//    assumption yields the correct dot product (self-canceling).
//  - bias folded as A[k=8]=1 (lane 0-group constant) x B[k=8][n]=bias_n.
// Gate order i,f,g,o; g-gate weights pre-scaled 2*L2E, others L2E; then
// act = sig2(S) (and 2*sig-1 for g) - the R7/R10-verified convention.
// Phase 1 = R4's verbatim (verified, writes sX f16-packed in LDS).
// ---------------------------------------------------------------------------
__global__ __launch_bounds__(256, 1) void fused_kernel(
    const float* __restrict__ x, const float* __restrict__ Wih1,
    const float* __restrict__ Whh1, const float* __restrict__ bih1,
    const float* __restrict__ bhh1, const float* __restrict__ Wih2,
    const float* __restrict__ Whh2, const float* __restrict__ bih2,
    const float* __restrict__ bhh2, const float* __restrict__ Wd1,
    const float* __restrict__ bd1, const float* __restrict__ Wd2,
    const float* __restrict__ bd2, float* __restrict__ out) {
  __shared__ __align__(16) int4 sXi[1025];       // h1 sequence f16 (16.4 KB)
  __shared__ __align__(16) _Float16 sHh[2][128]; // double-buffered h, f16

  const int b = blockIdx.x;
  const int t = threadIdx.x;

  // ======================== Phase 1: lstm1 (R4 verbatim) ====================
  {
    int whh2[128];
#pragma unroll
    for (int r = 0; r < 32; ++r) {
      const float s = (r >> 3) == 2 ? 2.f * L2E : L2E;
#pragma unroll
      for (int j = 0; j < 4; ++j) {
        float2 v = ((const float2*)(Whh1 + r * 8))[j];
        whh2[r * 4 + j] = packf16(v.x * s, v.y * s);
      }
    }
    int wxb[32];
#pragma unroll
    for (int r = 0; r < 32; ++r) {
      const float s = (r >> 3) == 2 ? 2.f * L2E : L2E;
      wxb[r] = packf16(Wih1[r] * s, (bih1[r] + bhh1[r]) * s);
    }
#pragma unroll
    for (int i = 0; i < 128; i += 8)
      asm volatile("" : "+v"(whh2[i]), "+v"(whh2[i + 1]), "+v"(whh2[i + 2]),
                        "+v"(whh2[i + 3]), "+v"(whh2[i + 4]), "+v"(whh2[i + 5]),
                        "+v"(whh2[i + 6]), "+v"(whh2[i + 7]));

#pragma unroll 1
    for (int ch = 0; ch < 4; ++ch) {
      const int c = ch * 256 + t;  // chain index within this batch row
      const float* __restrict__ xp = x + ((size_t)b * 1024 + c) * 16;
      float cc[8];
      int h2[4];
#pragma unroll
      for (int k = 0; k < 8; ++k) cc[k] = 0.f;
#pragma unroll
      for (int j = 0; j < 4; ++j) h2[j] = 0;

      float xv = xp[0];
#pragma unroll 1
      for (int u = 0; u < 16; ++u) {
        float xnl = xp[(u + 1) & 15];
        const int xt1 = packf16(xv, 1.f);
        float hn[8];
#pragma unroll
        for (int k = 0; k < 8; ++k) {
          float acc[4];
#pragma unroll
          for (int gi = 0; gi < 4; ++gi) {
            const int r = gi * 8 + k;
            float a = dot2(wxb[r], xt1, 0.f);
            a = dot2(whh2[r * 4 + 0], h2[0], a);
            a = dot2(whh2[r * 4 + 1], h2[1], a);
            a = dot2(whh2[r * 4 + 2], h2[2], a);
            a = dot2(whh2[r * 4 + 3], h2[3], a);
            acc[gi] = a;
          }
          float iv = sig2(acc[0]), fv = sig2(acc[1]);
          float gv = fmaf(2.f, sig2(acc[2]), -1.f), ov = sig2(acc[3]);
          cc[k] = fmaf(fv, cc[k], iv * gv);
          hn[k] = ov * tanhc(cc[k]);
        }
#pragma unroll
        for (int j = 0; j < 4; ++j) h2[j] = packf16(hn[2 * j], hn[2 * j + 1]);
        xv = xnl;
      }
      int4 o;
      o.x = h2[0]; o.y = h2[1]; o.z = h2[2]; o.w = h2[3];
      sXi[c] = o;  // 8 f16: h[0..7] of chain c
    }
  }

  // ======================== Phase 2: lstm2 (MFMA) ==========================
  const int w = t >> 6;          // wave id 0..3 (covers m in [32w, 32w+32))
  const int lane = t & 63;
  const int lc = lane & 15;      // A-row / B-col within tile
  const int lk = lane >> 4;      // k-chunk selector (8 f16 per chunk)

  // B fragments: bh[kt][nt] covers K-tile kt (32 k) x N-tile nt (16 cols).
  // Wave's col n_local = nt*16 + lc -> gate g = nt>>1, m = w*32+(nt&1)*16+lc,
  // global row = g*128+m. k within tile = lk*8 + i (contiguous f32 in Whh2).
  f16x8v bh[4][8];
  f16x8v bx[8];
#pragma unroll
  for (int nt = 0; nt < 8; ++nt) {
    const int g = nt >> 1;
    const int row = g * 128 + w * 32 + (nt & 1) * 16 + lc;
    const float s = (g == 2) ? 2.f * L2E : L2E;
#pragma unroll
    for (int kt = 0; kt < 4; ++kt) {
      const float* p = Whh2 + (size_t)row * 128 + kt * 32 + lk * 8;
      f16x8v f;
#pragma unroll
      for (int i = 0; i < 8; ++i) f[i] = (_Float16)(p[i] * s);
      bh[kt][nt] = f;
    }
    // X-tile (K=32): k 0..7 = Wih2 row, k==8 = bias, rest 0.
    f16x8v fx = {};
    if (lk == 0) {
      const float* px = Wih2 + (size_t)row * 8;
#pragma unroll
      for (int i = 0; i < 8; ++i) fx[i] = (_Float16)(px[i] * s);
    } else if (lk == 1) {
      fx[0] = (_Float16)((bih2[row] + bhh2[row]) * s);
    }
    bx[nt] = fx;
  }

  // A X-fragment constant part: A[row 0][k=8] = 1.0 (bias multiplier).
  f16x8v xb1 = {};
  if (lc == 0 && lk == 1) xb1[0] = (_Float16)1.f;

  // A h-fragments: row 0 = h (lanes lc==0), rows 1..15 = 0.
  f16x8v ah0 = {}, ah1 = {}, ah2 = {}, ah3 = {};
  float cst0 = 0.f, cst1 = 0.f;  // cell state (lanes 0..15 of each wave)

  __syncthreads();  // sXi fully written by phase 1
  int4 xr_cur = sXi[0];

#define LSTM2_STEP(BUF, NEXTI)                                               \
  {                                                                          \
    f16x8v xa = (lc == 0 && lk == 0)                                         \
                    ? __builtin_bit_cast(f16x8v, xr_cur) : xb1;              \
    f32x4v acc0 = {}, acc1 = {}, acc2 = {}, acc3 = {};                       \
    f32x4v acc4 = {}, acc5 = {}, acc6 = {}, acc7 = {};                       \
    acc0 = __builtin_amdgcn_mfma_f32_16x16x32_f16(ah0, bh[0][0], acc0, 0, 0, 0); \
    acc0 = __builtin_amdgcn_mfma_f32_16x16x32_f16(ah1, bh[1][0], acc0, 0, 0, 0); \
    acc0 = __builtin_amdgcn_mfma_f32_16x16x32_f16(ah2, bh[2][0], acc0, 0, 0, 0); \
    acc0 = __builtin_amdgcn_mfma_f32_16x16x32_f16(ah3, bh[3][0], acc0, 0, 0, 0); \
    acc0 = __builtin_amdgcn_mfma_f32_16x16x32_f16(xa, bx[0], acc0, 0, 0, 0); \
    acc1 = __builtin_amdgcn_mfma_f32_16x16x32_f16(ah0, bh[0][1], acc1, 0, 0, 0); \
    acc1 = __builtin_amdgcn_mfma_f32_16x16x32_f16(ah1, bh[1][1], acc1, 0, 0, 0); \
    acc1 = __builtin_amdgcn_mfma_f32_16x16x32_f16(ah2, bh[2][1], acc1, 0, 0, 0); \
    acc1 = __builtin_amdgcn_mfma_f32_16x16x32_f16(ah3, bh[3][1], acc1, 0, 0, 0); \
    acc1 = __builtin_amdgcn_mfma_f32_16x16x32_f16(xa, bx[1], acc1, 0, 0, 0); \
    acc2 = __builtin_amdgcn_mfma_f32_16x16x32_f16(ah0, bh[0][2], acc2, 0, 0, 0); \
    acc2 = __builtin_amdgcn_mfma_f32_16x16x32_f16(ah1, bh[1][2], acc2, 0, 0, 0); \
    acc2 = __builtin_amdgcn_mfma_f32_16x16x32_f16(ah2, bh[2][2], acc2, 0, 0, 0); \
    acc2 = __builtin_amdgcn_mfma_f32_16x16x32_f16(ah3, bh[3][2], acc2, 0, 0, 0); \
    acc2 = __builtin_amdgcn_mfma_f32_16x16x32_f16(xa, bx[2], acc2, 0, 0, 0); \
    acc3 = __builtin_amdgcn_mfma_f32_16x16x32_f16(ah0, bh[0][3], acc3, 0, 0, 0); \
    acc3 = __builtin_amdgcn_mfma_f32_16x16x32_f16(ah1, bh[1][3], acc3, 0, 0, 0); \
    acc3 = __builtin_amdgcn_mfma_f32_16x16x32_f16(ah2, bh[2][3], acc3, 0, 0, 0); \
    acc3 = __builtin_amdgcn_mfma_f32_16x16x32_f16(ah3, bh[3][3], acc3, 0, 0, 0); \
    acc3 = __builtin_amdgcn_mfma_f32_16x16x32_f16(xa, bx[3], acc3, 0, 0, 0); \
    acc4 = __builtin_amdgcn_mfma_f32_16x16x32_f16(ah0, bh[0][4], acc4, 0, 0, 0); \
    acc4 = __builtin_amdgcn_mfma_f32_16x16x32_f16(ah1, bh[1][4], acc4, 0, 0, 0); \
    acc4 = __builtin_amdgcn_mfma_f32_16x16x32_f16(ah2, bh[2][4], acc4, 0, 0, 0); \
    acc4 = __builtin_amdgcn_mfma_f32_16x16x32_f16(ah3, bh[3][4], acc4, 0, 0, 0); \
    acc4 = __builtin_amdgcn_mfma_f32_16x16x32_f16(xa, bx[4], acc4, 0, 0, 0); \
    acc5 = __builtin_amdgcn_mfma_f32_16x16x32_f16(ah0, bh[0][5], acc5, 0, 0, 0); \
    acc5 = __builtin_amdgcn_mfma_f32_16x16x32_f16(ah1, bh[1][5], acc5, 0, 0, 0); \
    acc5 = __builtin_amdgcn_mfma_f32_16x16x32_f16(ah2, bh[2][5], acc5, 0, 0, 0); \
    acc5 = __builtin_amdgcn_mfma_f32_16x16x32_f16(ah3, bh[3][5], acc5, 0, 0, 0); \
    acc5 = __builtin_amdgcn_mfma_f32_16x16x32_f16(xa, bx[5], acc5, 0, 0, 0); \
    acc6 = __builtin_amdgcn_mfma_f32_16x16x32_f16(ah0, bh[0][6], acc6, 0, 0, 0); \
    acc6 = __builtin_amdgcn_mfma_f32_16x16x32_f16(ah1, bh[1][6], acc6, 0, 0, 0); \
    acc6 = __builtin_amdgcn_mfma_f32_16x16x32_f16(ah2, bh[2][6], acc6, 0, 0, 0); \
    acc6 = __builtin_amdgcn_mfma_f32_16x16x32_f16(ah3, bh[3][6], acc6, 0, 0, 0); \
    acc6 = __builtin_amdgcn_mfma_f32_16x16x32_f16(xa, bx[6], acc6, 0, 0, 0); \
    acc7 = __builtin_amdgcn_mfma_f32_16x16x32_f16(ah0, bh[0][7], acc7, 0, 0, 0); \
    acc7 = __builtin_amdgcn_mfma_f32_16x16x32_f16(ah1, bh[1][7], acc7, 0, 0, 0); \
    acc7 = __builtin_amdgcn_mfma_f32_16x16x32_f16(ah2, bh[2][7], acc7, 0, 0, 0); \
    acc7 = __builtin_amdgcn_mfma_f32_16x16x32_f16(ah3, bh[3][7], acc7, 0, 0, 0); \
    acc7 = __builtin_amdgcn_mfma_f32_16x16x32_f16(xa, bx[7], acc7, 0, 0, 0); \
    /* pointwise: row 0 -> (lane>>4)==0 && reg j==0 -> lanes 0..15, elem 0 */\
    if (lane < 16) {                                                         \
      float iv0 = sig2(acc0[0]), fv0 = sig2(acc2[0]);                        \
      float gv0 = fmaf(2.f, sig2(acc4[0]), -1.f), ov0 = sig2(acc6[0]);       \
      cst0 = fmaf(fv0, cst0, iv0 * gv0);                                     \
      sHh[BUF][w * 32 + lane] = (_Float16)(ov0 * tanhc(cst0));               \
      float iv1 = sig2(acc1[0]), fv1 = sig2(acc3[0]);                        \
      float gv1 = fmaf(2.f, sig2(acc5[0]), -1.f), ov1 = sig2(acc7[0]);       \
      cst1 = fmaf(fv1, cst1, iv1 * gv1);                                     \
      sHh[BUF][w * 32 + 16 + lane] = (_Float16)(ov1 * tanhc(cst1));          \
    }                                                                        \
    __syncthreads();                                                         \
    if (lc == 0) {                                                           \
      const int4* hb = (const int4*)sHh[BUF];                                \
      ah0 = __builtin_bit_cast(f16x8v, hb[0 + lk]);                          \
      ah1 = __builtin_bit_cast(f16x8v, hb[4 + lk]);                          \
      ah2 = __builtin_bit_cast(f16x8v, hb[8 + lk]);                          \
      ah3 = __builtin_bit_cast(f16x8v, hb[12 + lk]);                         \
    }                                                                        \
    xr_cur = sXi[NEXTI];                                                     \
  }

#pragma unroll 1
  for (int ts2 = 0; ts2 < 512; ++ts2) {
    LSTM2_STEP(0, 2 * ts2 + 1)
    LSTM2_STEP(1, 2 * ts2 + 2)
  }
#undef LSTM2_STEP

  // Epilogue: out[b] = (h @ Wd1.T + bd1) @ Wd2.T + bd2; h_T is in sHh[1].
  if (t < 64) {
    float a = bd1[t];
#pragma unroll
    for (int k = 0; k < 128; ++k)
      a = fmaf(Wd1[t * 128 + k], (float)sHh[1][k], a);
    float v = a * Wd2[t];
#pragma unroll
    for (int off = 32; off > 0; off >>= 1) v += __shfl_down(v, off);
    if (t == 0) out[b] = v + bd2[0];
  }
}

extern "C" void kernel_launch(void* const* d_in, const int* in_sizes, int n_in,
                              void* d_out, int out_size, void* d_ws, size_t ws_size,
                              hipStream_t stream) {
  const float* x    = (const float*)d_in[0];
  // d_in[1] is the unused python scalar `data`
  const float* Wih1 = (const float*)d_in[2];
  const float* Whh1 = (const float*)d_in[3];
  const float* bih1 = (const float*)d_in[4];
  const float* bhh1 = (const float*)d_in[5];
  const float* Wih2 = (const float*)d_in[6];
  const float* Whh2 = (const float*)d_in[7];
  const float* bih2 = (const float*)d_in[8];
  const float* bhh2 = (const float*)d_in[9];
  const float* W1   = (const float*)d_in[10];
  const float* b1   = (const float*)d_in[11];
  const float* W2   = (const float*)d_in[12];
  const float* b2   = (const float*)d_in[13];
  float* out = (float*)d_out;

  fused_kernel<<<256, 256, 0, stream>>>(x, Wih1, Whh1, bih1, bhh1,
                                        Wih2, Whh2, bih2, bhh2,
                                        W1, b1, W2, b2, out);
}